// Round 3
// baseline (125.362 us; speedup 1.0000x reference)
//
#include <hip/hip_runtime.h>

// Problem dims (compile-time)
#define BATCH 1024
#define NELEC 64
#define DF    32     // backflow feature dim D
#define NION  16
#define NORB  32
#define NE    32     // NELEC / NSPIN
#define NSB   2048   // NSPIN * BATCH
#define FACT_FLOATS (NSB * NE * NORB)       // 2M floats = 8 MB per factor
#define M_PAD 8192                           // Gram region (6144 used), 32 KB
#define WS_NEEDED ((size_t)(M_PAD + 3 * FACT_FLOATS) * 4)

#define FMA4(acc, sc, v) { acc.x += (sc)*(v).x; acc.y += (sc)*(v).y; acc.z += (sc)*(v).z; acc.w += (sc)*(v).w; }

// ---------------------------------------------------------------------------
// K0: Gram matrices  M[s][i][o][6] = {m00,m11,m22, 2*m01, 2*m02, 2*m12}
//     where M[d,d'] = sum_e W_env[s,i,d,o,e] * W_env[s,i,d',o,e]
// ---------------------------------------------------------------------------
__global__ __launch_bounds__(256) void k0_gram(
    const float* __restrict__ W_env,   // (2, NION, 3, NORB, 3)
    float* __restrict__ Mg)            // (2, NION, NORB, 6)
{
    int id = blockIdx.x * 256 + threadIdx.x;
    if (id >= 2 * NION * NORB) return;
    int s = id >> 9, rem = id & 511, i = rem >> 5, o = rem & 31;
    const float* base = W_env + ((size_t)((s*NION + i) * 3) * NORB + o) * 3;
    float a0[3], a1[3], a2[3];
    #pragma unroll
    for (int e = 0; e < 3; ++e) {
        a0[e] = base[e];          // d=0 ; d-stride = NORB*3 = 96
        a1[e] = base[96 + e];
        a2[e] = base[192 + e];
    }
    float* out = Mg + ((size_t)(s*NION + i) * NORB + o) * 6;
    out[0] = a0[0]*a0[0] + a0[1]*a0[1] + a0[2]*a0[2];
    out[1] = a1[0]*a1[0] + a1[1]*a1[1] + a1[2]*a1[2];
    out[2] = a2[0]*a2[0] + a2[1]*a2[1] + a2[2]*a2[2];
    out[3] = 2.f*(a0[0]*a1[0] + a0[1]*a1[1] + a0[2]*a1[2]);
    out[4] = 2.f*(a0[0]*a2[0] + a0[1]*a2[1] + a0[2]*a2[2]);
    out[5] = 2.f*(a1[0]*a2[0] + a1[1]*a2[1] + a1[2]*a2[2]);
}

// ---------------------------------------------------------------------------
// K1: factors for TWO walkers per block (same spin). Thread = (n, o-quad).
//   U[n,o] = sum_d x[n,d] W0[d,o] ; V likewise with W1; all b128 LDS reads.
//   E[n,o] = sum_i exp(-sqrt(r^T M r)) * w_ion ;  W = (V+b)*E
// ---------------------------------------------------------------------------
__global__ __launch_bounds__(256, 4) void k1_factors2(
    const float* __restrict__ x,      // (B, NELEC, D)
    const float* __restrict__ r_ei,   // (B, NELEC, NION, 3)
    const float* __restrict__ W_orb,  // (2, 2D, NORB)
    const float* __restrict__ b_orb,  // (2, NORB)
    const float* __restrict__ w_ion,  // (2, NION)
    const float* __restrict__ Mg,     // (2, NION, NORB, 6)
    float* __restrict__ Uf, float* __restrict__ Ef, float* __restrict__ Wf)
{
    __shared__ float sworb[2*DF*NORB];   // 8 KB   [d(64)][o(32)]
    __shared__ float sM[NION*NORB*6];    // 12 KB  [i][o][6]
    __shared__ float sr[64*52];          // 13 KB  [w*32+n][52] (48 used)
    __shared__ float swion[NION];

    const int t   = threadIdx.x;
    const int blk = blockIdx.x;
    const int s   = blk >> 9;
    const int b0  = (blk & 511) * 2;

    // ---- stage ----
    {
        const float4* g = (const float4*)(W_orb + (size_t)s * 2*DF*NORB);
        float4* d = (float4*)sworb;
        d[t] = g[t]; d[t + 256] = g[t + 256];
    }
    {
        const float4* g = (const float4*)(Mg + (size_t)s * NION*NORB*6);
        float4* d = (float4*)sM;
        d[t] = g[t]; d[t + 256] = g[t + 256]; d[t + 512] = g[t + 512];
    }
    {
        const int row = t >> 2, seg = t & 3;       // row = w*32 + n
        const int w = row >> 5, nn = row & 31;
        const float4* g = (const float4*)(r_ei + ((size_t)(b0 + w)*NELEC + s*NE + nn) * NION * 3);
        float4 v0 = g[seg*3 + 0], v1 = g[seg*3 + 1], v2 = g[seg*3 + 2];
        float4* d = (float4*)(sr + row*52 + seg*12);
        d[0] = v0; d[1] = v1; d[2] = v2;
    }
    if (t < NION) swion[t] = w_ion[s*NION + t];
    __syncthreads();

    const int n  = t >> 3;
    const int o0 = (t & 7) * 4;

    // ---- GEMM: U,V for both walkers (b128 LDS reads, x from global/L1) ----
    float4 uA = {0,0,0,0}, uB = {0,0,0,0}, vA = {0,0,0,0}, vB = {0,0,0,0};
    const float* xrowA = x + ((size_t)(b0 + 0)*NELEC + s*NE + n) * DF;
    const float* xrowB = x + ((size_t)(b0 + 1)*NELEC + s*NE + n) * DF;
    #pragma unroll
    for (int db = 0; db < 8; ++db) {
        const float4 xa = *(const float4*)(xrowA + db*4);
        const float4 xb = *(const float4*)(xrowB + db*4);
        #pragma unroll
        for (int k = 0; k < 4; ++k) {
            const int d = db*4 + k;
            const float4 w0 = *(const float4*)(sworb + d*NORB + o0);
            const float4 w1 = *(const float4*)(sworb + (DF + d)*NORB + o0);
            const float xk0 = (&xa.x)[k], xk1 = (&xb.x)[k];
            FMA4(uA, xk0, w0); FMA4(vA, xk0, w1);
            FMA4(uB, xk1, w0); FMA4(vB, xk1, w1);
        }
    }

    // ---- envelope via Gram quadratic form ----
    float4 eA = {0,0,0,0}, eB = {0,0,0,0};
    const float* rpA = sr + n*52;
    const float* rpB = sr + (32 + n)*52;
    #pragma unroll
    for (int ig = 0; ig < 4; ++ig) {
        float rA[12], rB[12];
        *(float4*)(rA + 0) = *(const float4*)(rpA + ig*12 + 0);
        *(float4*)(rA + 4) = *(const float4*)(rpA + ig*12 + 4);
        *(float4*)(rA + 8) = *(const float4*)(rpA + ig*12 + 8);
        *(float4*)(rB + 0) = *(const float4*)(rpB + ig*12 + 0);
        *(float4*)(rB + 4) = *(const float4*)(rpB + ig*12 + 4);
        *(float4*)(rB + 8) = *(const float4*)(rpB + ig*12 + 8);
        #pragma unroll
        for (int ii = 0; ii < 4; ++ii) {
            const int i = ig*4 + ii;
            const float* mp = sM + (size_t)(i*NORB + o0) * 6;   // 24 contiguous floats
            float mA[24];
            *(float4*)(mA +  0) = *(const float4*)(mp +  0);
            *(float4*)(mA +  4) = *(const float4*)(mp +  4);
            *(float4*)(mA +  8) = *(const float4*)(mp +  8);
            *(float4*)(mA + 12) = *(const float4*)(mp + 12);
            *(float4*)(mA + 16) = *(const float4*)(mp + 16);
            *(float4*)(mA + 20) = *(const float4*)(mp + 20);
            const float wi = swion[i];
            // walker A
            {
                const float r0 = rA[ii*3+0], r1 = rA[ii*3+1], r2 = rA[ii*3+2];
                const float q00 = r0*r0, q11 = r1*r1, q22 = r2*r2;
                const float q01 = r0*r1, q02 = r0*r2, q12 = r1*r2;
                #pragma unroll
                for (int j = 0; j < 4; ++j) {
                    const float* m = mA + j*6;
                    float d2 = m[0]*q00 + m[1]*q11 + m[2]*q22
                             + m[3]*q01 + m[4]*q02 + m[5]*q12;
                    d2 = fmaxf(d2, 0.f);
                    (&eA.x)[j] += wi * __expf(-sqrtf(d2));
                }
            }
            // walker B
            {
                const float r0 = rB[ii*3+0], r1 = rB[ii*3+1], r2 = rB[ii*3+2];
                const float q00 = r0*r0, q11 = r1*r1, q22 = r2*r2;
                const float q01 = r0*r1, q02 = r0*r2, q12 = r1*r2;
                #pragma unroll
                for (int j = 0; j < 4; ++j) {
                    const float* m = mA + j*6;
                    float d2 = m[0]*q00 + m[1]*q11 + m[2]*q22
                             + m[3]*q01 + m[4]*q02 + m[5]*q12;
                    d2 = fmaxf(d2, 0.f);
                    (&eB.x)[j] += wi * __expf(-sqrtf(d2));
                }
            }
        }
    }

    // ---- write factors (perfectly coalesced: offset = t*4 floats) ----
    const float4 bq = *(const float4*)(b_orb + s*NORB + o0);
    const size_t wbase = ((size_t)(s*BATCH + b0)) * (NE*NORB) + (size_t)t * 4;
    float4 wA, wB;
    wA.x = (vA.x + bq.x) * eA.x; wA.y = (vA.y + bq.y) * eA.y;
    wA.z = (vA.z + bq.z) * eA.z; wA.w = (vA.w + bq.w) * eA.w;
    wB.x = (vB.x + bq.x) * eB.x; wB.y = (vB.y + bq.y) * eB.y;
    wB.z = (vB.z + bq.z) * eB.z; wB.w = (vB.w + bq.w) * eB.w;
    *(float4*)(Uf + wbase)             = uA;
    *(float4*)(Ef + wbase)             = eA;
    *(float4*)(Wf + wbase)             = wA;
    *(float4*)(Uf + wbase + NE*NORB)   = uB;
    *(float4*)(Ef + wbase + NE*NORB)   = eB;
    *(float4*)(Wf + wbase + NE*NORB)   = wB;
}

// ---------------------------------------------------------------------------
// K2: pure streaming expansion  out[p,i,o] = U[p,o]*E[i,o] + W[i,o]
// ---------------------------------------------------------------------------
__global__ __launch_bounds__(256) void k2_expand(
    const float* __restrict__ Uf,
    const float* __restrict__ Ef,
    const float* __restrict__ Wf,
    float* __restrict__ out)
{
    __shared__ float sU[NE][NORB];   // 4 KB
    const int t   = threadIdx.x;
    const int blk = blockIdx.x;
    const size_t base = (size_t)blk * (NE*NORB);

    ((float4*)&sU[0][0])[t] = ((const float4*)(Uf + base))[t];
    const float4 e4 = ((const float4*)(Ef + base))[t];
    const float4 w4 = ((const float4*)(Wf + base))[t];
    __syncthreads();

    const int o0 = (t & 7) * 4;
    float4* outp = (float4*)(out + (size_t)blk * (NE*NE*NORB));
    #pragma unroll
    for (int p = 0; p < NE; ++p) {
        const float4 u4 = *(const float4*)&sU[p][o0];
        float4 r;
        r.x = u4.x*e4.x + w4.x;
        r.y = u4.y*e4.y + w4.y;
        r.z = u4.z*e4.z + w4.z;
        r.w = u4.w*e4.w + w4.w;
        outp[p*256 + t] = r;
    }
}

// ---------------------------------------------------------------------------
// Fallback: proven single fused kernel (used only if ws is too small)
// ---------------------------------------------------------------------------
__global__ __launch_bounds__(256) void deq_orbital_fused(
    const float* __restrict__ x, const float* __restrict__ r_ei,
    const float* __restrict__ W_orb, const float* __restrict__ b_orb,
    const float* __restrict__ W_env, const float* __restrict__ w_ion,
    float* __restrict__ out)
{
    __shared__ float sx[NE][DF];
    __shared__ float sworb[2*DF][NORB];
    __shared__ float sr[NE][NION*3];
    __shared__ float swe[NION*3*NORB*3];
    __shared__ float sU[NE][NORB];
    __shared__ float sV[NE][NORB];
    __shared__ float sE[NE][NORB];
    __shared__ float sb[NORB];
    __shared__ float swion[NION];

    const int t   = threadIdx.x;
    const int blk = blockIdx.x;
    const int s   = blk >> 10;
    const int b   = blk & (BATCH - 1);

    {
        const float4* xg = (const float4*)(x + (size_t)(b*NELEC + s*NE) * DF);
        ((float4*)&sx[0][0])[t] = xg[t];
    }
    {
        const float4* wg = (const float4*)(W_orb + (size_t)s * 2*DF*NORB);
        float4* d = (float4*)&sworb[0][0];
        d[t] = wg[t]; d[t + 256] = wg[t + 256];
    }
    {
        const float4* rg = (const float4*)(r_ei + (size_t)(b*NELEC + s*NE) * NION * 3);
        float4* d = (float4*)&sr[0][0];
        d[t] = rg[t];
        if (t < 128) d[t + 256] = rg[t + 256];
    }
    {
        const float4* weg = (const float4*)(W_env + (size_t)s * NION*3*NORB*3);
        float4* d = (float4*)swe;
        for (int j = t; j < 1152; j += 256) d[j] = weg[j];
    }
    if (t < NORB) sb[t]    = b_orb[s*NORB + t];
    if (t < NION) swion[t] = w_ion[s*NION + t];
    __syncthreads();

    const int o  = t & 31;
    const int ng = t >> 5;
    float u_acc[4], v_acc[4];
    #pragma unroll
    for (int uu = 0; uu < 4; ++uu) { u_acc[uu] = 0.f; v_acc[uu] = 0.f; }
    #pragma unroll
    for (int d = 0; d < DF; ++d) {
        const float w0 = sworb[d][o];
        const float w1 = sworb[DF + d][o];
        #pragma unroll
        for (int uu = 0; uu < 4; ++uu) {
            const float xv = sx[ng*4 + uu][d];
            u_acc[uu] += xv * w0;
            v_acc[uu] += xv * w1;
        }
    }
    #pragma unroll
    for (int uu = 0; uu < 4; ++uu) {
        sU[ng*4 + uu][o] = u_acc[uu];
        sV[ng*4 + uu][o] = v_acc[uu];
    }
    #pragma unroll
    for (int uu = 0; uu < 4; ++uu) {
        const int nn = ng*4 + uu;
        float acc = 0.f;
        #pragma unroll
        for (int i = 0; i < NION; ++i) {
            const float r0 = sr[nn][i*3 + 0];
            const float r1 = sr[nn][i*3 + 1];
            const float r2 = sr[nn][i*3 + 2];
            const float* wp = &swe[i*3*NORB*3 + o*3];
            const float s0 = r0*wp[0] + r1*wp[NORB*3    ] + r2*wp[2*NORB*3    ];
            const float s1 = r0*wp[1] + r1*wp[NORB*3 + 1] + r2*wp[2*NORB*3 + 1];
            const float s2 = r0*wp[2] + r1*wp[NORB*3 + 2] + r2*wp[2*NORB*3 + 2];
            const float dist = sqrtf(s0*s0 + s1*s1 + s2*s2);
            acc += __expf(-dist) * swion[i];
        }
        sE[nn][o] = acc;
        sV[nn][o] = (v_acc[uu] + sb[o]) * acc;
    }
    __syncthreads();

    const int io = t >> 3;
    const int o0 = (t & 7) * 4;
    const float4 e4 = *(const float4*)&sE[io][o0];
    const float4 w4 = *(const float4*)&sV[io][o0];
    float4* outp = (float4*)(out + (size_t)blk * (NE*NE*NORB));
    #pragma unroll
    for (int p = 0; p < NE; ++p) {
        const float4 u4 = *(const float4*)&sU[p][o0];
        float4 r;
        r.x = u4.x*e4.x + w4.x;
        r.y = u4.y*e4.y + w4.y;
        r.z = u4.z*e4.z + w4.z;
        r.w = u4.w*e4.w + w4.w;
        outp[p*256 + t] = r;
    }
}

extern "C" void kernel_launch(void* const* d_in, const int* in_sizes, int n_in,
                              void* d_out, int out_size, void* d_ws, size_t ws_size,
                              hipStream_t stream) {
    const float* x     = (const float*)d_in[0];
    const float* r_ei  = (const float*)d_in[1];
    const float* W_orb = (const float*)d_in[2];
    const float* b_orb = (const float*)d_in[3];
    const float* W_env = (const float*)d_in[4];
    const float* w_ion = (const float*)d_in[5];
    float* out = (float*)d_out;

    if (ws_size >= WS_NEEDED) {
        float* Mg = (float*)d_ws;
        float* Uf = Mg + M_PAD;
        float* Ef = Uf + FACT_FLOATS;
        float* Wf = Ef + FACT_FLOATS;
        k0_gram<<<4, 256, 0, stream>>>(W_env, Mg);
        k1_factors2<<<1024, 256, 0, stream>>>(x, r_ei, W_orb, b_orb, w_ion, Mg,
                                              Uf, Ef, Wf);
        k2_expand<<<NSB, 256, 0, stream>>>(Uf, Ef, Wf, out);
    } else {
        deq_orbital_fused<<<NSB, 256, 0, stream>>>(x, r_ei, W_orb, b_orb,
                                                   W_env, w_ion, out);
    }
}

// Round 4
// 93.225 us; speedup vs baseline: 1.3447x; 1.3447x over previous
//
#include <hip/hip_runtime.h>

// Problem dims (compile-time)
#define BATCH 1024
#define NELEC 64
#define DF    32     // backflow feature dim D
#define NION  16
#define NORB  32
#define NE    32     // NELEC / NSPIN
#define NSB   2048   // NSPIN * BATCH
#define FACT_FLOATS (NSB * NE * NORB)       // 2M floats = 8 MB per factor
#define M_PAD 8192                           // Gram region (6144 used)
#define WS_NEEDED ((size_t)(M_PAD + 3 * FACT_FLOATS) * 4)

// ---------------------------------------------------------------------------
// K0: Gram matrices, SoA layout  Mg[s][i][m][o], m in 0..5 =
//     {m00, m11, m22, 2*m01, 2*m02, 2*m12},  m_dd' = sum_e A[d,e]*A[d',e]
// ---------------------------------------------------------------------------
__global__ __launch_bounds__(256) void k0_gram(
    const float* __restrict__ W_env,   // (2, NION, 3, NORB, 3)
    float* __restrict__ Mg)            // (2, NION, 6, NORB)
{
    int id = blockIdx.x * 256 + threadIdx.x;
    if (id >= 2 * NION * NORB) return;
    int s = id >> 9, rem = id & 511, i = rem >> 5, o = rem & 31;
    const float* base = W_env + ((size_t)((s*NION + i) * 3) * NORB + o) * 3;
    float a0[3], a1[3], a2[3];
    #pragma unroll
    for (int e = 0; e < 3; ++e) {
        a0[e] = base[e];           // d-stride = NORB*3 = 96
        a1[e] = base[96 + e];
        a2[e] = base[192 + e];
    }
    float* out = Mg + ((size_t)(s*NION + i) * 6) * NORB + o;
    out[0*NORB] = a0[0]*a0[0] + a0[1]*a0[1] + a0[2]*a0[2];
    out[1*NORB] = a1[0]*a1[0] + a1[1]*a1[1] + a1[2]*a1[2];
    out[2*NORB] = a2[0]*a2[0] + a2[1]*a2[1] + a2[2]*a2[2];
    out[3*NORB] = 2.f*(a0[0]*a1[0] + a0[1]*a1[1] + a0[2]*a1[2]);
    out[4*NORB] = 2.f*(a0[0]*a2[0] + a0[1]*a2[1] + a0[2]*a2[2]);
    out[5*NORB] = 2.f*(a1[0]*a2[0] + a1[1]*a2[1] + a1[2]*a2[2]);
}

// ---------------------------------------------------------------------------
// K1: one walker-spin per block. Thread = (n = t>>3, orbital quad o0 = (t&7)*4).
//   U[n,o] = sum_d x[n,d] W0[d,o]; V likewise; E via Gram quadratic form;
//   W = (V+b)*E.  All LDS reads are 128B-contiguous b128 or 8-addr broadcast.
// ---------------------------------------------------------------------------
__global__ __launch_bounds__(256) void k1_factors(
    const float* __restrict__ x,      // (B, NELEC, D)
    const float* __restrict__ r_ei,   // (B, NELEC, NION, 3)
    const float* __restrict__ W_orb,  // (2, 2D, NORB)
    const float* __restrict__ b_orb,  // (2, NORB)
    const float* __restrict__ w_ion,  // (2, NION)
    const float* __restrict__ Mg,     // (2, NION, 6, NORB)
    float* __restrict__ Uf, float* __restrict__ Ef, float* __restrict__ Wf)
{
    __shared__ float sworb[2*DF*NORB];   // 8 KB   [d(64)][o(32)]
    __shared__ float sM[NION*6*NORB];    // 12 KB  [i][m][o]
    __shared__ float sr[NE*52];          // 6.5 KB [n][52] (48 used; 52%32=20 -> no conflict)
    __shared__ float swion[NION];

    const int t   = threadIdx.x;
    const int blk = blockIdx.x;
    const int s   = blk >> 10;
    const int b   = blk & (BATCH - 1);

    // ---- stage ----
    {
        const float4* g = (const float4*)(W_orb + (size_t)s * 2*DF*NORB);
        float4* d = (float4*)sworb;
        d[t] = g[t]; d[t + 256] = g[t + 256];
    }
    {
        const float4* g = (const float4*)(Mg + (size_t)s * NION*6*NORB);
        float4* d = (float4*)sM;
        d[t] = g[t]; d[t + 256] = g[t + 256]; d[t + 512] = g[t + 512];
    }
    if (t < 128) {
        const int row = t >> 2, seg = t & 3;
        const float4* g = (const float4*)(r_ei + ((size_t)b*NELEC + s*NE + row) * NION * 3);
        float4* d = (float4*)(sr + row*52 + seg*12);
        d[0] = g[seg*3 + 0]; d[1] = g[seg*3 + 1]; d[2] = g[seg*3 + 2];
    }
    if (t < NION) swion[t] = w_ion[s*NION + t];
    __syncthreads();

    const int n  = t >> 3;
    const int o0 = (t & 7) * 4;

    // ---- GEMM: U, V (x row via L1-cached global, W via b128 LDS) ----
    float u[4] = {0,0,0,0}, v[4] = {0,0,0,0};
    const float* xrow = x + ((size_t)b*NELEC + s*NE + n) * DF;
    #pragma unroll
    for (int db = 0; db < 8; ++db) {
        const float4 xa = *(const float4*)(xrow + db*4);
        #pragma unroll
        for (int k = 0; k < 4; ++k) {
            const int d = db*4 + k;
            const float4 w0 = *(const float4*)(sworb + d*NORB + o0);
            const float4 w1 = *(const float4*)(sworb + (DF + d)*NORB + o0);
            const float xk = (&xa.x)[k];
            u[0] += xk*w0.x; u[1] += xk*w0.y; u[2] += xk*w0.z; u[3] += xk*w0.w;
            v[0] += xk*w1.x; v[1] += xk*w1.y; v[2] += xk*w1.z; v[3] += xk*w1.w;
        }
    }

    // ---- envelope via Gram quadratic form (SoA: one m-float4 live at a time) ----
    float e[4] = {0,0,0,0};
    #pragma unroll
    for (int i = 0; i < NION; ++i) {
        const float r0 = sr[n*52 + i*3 + 0];
        const float r1 = sr[n*52 + i*3 + 1];
        const float r2 = sr[n*52 + i*3 + 2];
        const float q00 = r0*r0, q11 = r1*r1, q22 = r2*r2;
        const float q01 = r0*r1, q02 = r0*r2, q12 = r1*r2;
        const float* mp = sM + (size_t)(i*6) * NORB + o0;
        float d2[4];
        {
            const float4 m = *(const float4*)(mp + 0*NORB);
            d2[0] = m.x*q00; d2[1] = m.y*q00; d2[2] = m.z*q00; d2[3] = m.w*q00;
        }
        {
            const float4 m = *(const float4*)(mp + 1*NORB);
            d2[0] += m.x*q11; d2[1] += m.y*q11; d2[2] += m.z*q11; d2[3] += m.w*q11;
        }
        {
            const float4 m = *(const float4*)(mp + 2*NORB);
            d2[0] += m.x*q22; d2[1] += m.y*q22; d2[2] += m.z*q22; d2[3] += m.w*q22;
        }
        {
            const float4 m = *(const float4*)(mp + 3*NORB);
            d2[0] += m.x*q01; d2[1] += m.y*q01; d2[2] += m.z*q01; d2[3] += m.w*q01;
        }
        {
            const float4 m = *(const float4*)(mp + 4*NORB);
            d2[0] += m.x*q02; d2[1] += m.y*q02; d2[2] += m.z*q02; d2[3] += m.w*q02;
        }
        {
            const float4 m = *(const float4*)(mp + 5*NORB);
            d2[0] += m.x*q12; d2[1] += m.y*q12; d2[2] += m.z*q12; d2[3] += m.w*q12;
        }
        const float wi = swion[i];
        #pragma unroll
        for (int j = 0; j < 4; ++j) {
            const float dd = fmaxf(d2[j], 0.f);
            e[j] += wi * __expf(-sqrtf(dd));
        }
    }

    // ---- write factors (perfectly coalesced: element offset = t*4) ----
    const float4 bq = *(const float4*)(b_orb + s*NORB + o0);
    const size_t wbase = (size_t)blk * (NE*NORB) + (size_t)t * 4;
    float4 uo, eo, wo;
    uo.x = u[0]; uo.y = u[1]; uo.z = u[2]; uo.w = u[3];
    eo.x = e[0]; eo.y = e[1]; eo.z = e[2]; eo.w = e[3];
    wo.x = (v[0] + bq.x) * e[0];
    wo.y = (v[1] + bq.y) * e[1];
    wo.z = (v[2] + bq.z) * e[2];
    wo.w = (v[3] + bq.w) * e[3];
    *(float4*)(Uf + wbase) = uo;
    *(float4*)(Ef + wbase) = eo;
    *(float4*)(Wf + wbase) = wo;
}

// ---------------------------------------------------------------------------
// K2: pure streaming expansion  out[p,i,o] = U[p,o]*E[i,o] + W[i,o]
// ---------------------------------------------------------------------------
__global__ __launch_bounds__(256) void k2_expand(
    const float* __restrict__ Uf,
    const float* __restrict__ Ef,
    const float* __restrict__ Wf,
    float* __restrict__ out)
{
    __shared__ float sU[NE][NORB];   // 4 KB
    const int t   = threadIdx.x;
    const int blk = blockIdx.x;
    const size_t base = (size_t)blk * (NE*NORB);

    ((float4*)&sU[0][0])[t] = ((const float4*)(Uf + base))[t];
    const float4 e4 = ((const float4*)(Ef + base))[t];
    const float4 w4 = ((const float4*)(Wf + base))[t];
    __syncthreads();

    const int o0 = (t & 7) * 4;
    float4* outp = (float4*)(out + (size_t)blk * (NE*NE*NORB));
    #pragma unroll
    for (int p = 0; p < NE; ++p) {
        const float4 u4 = *(const float4*)&sU[p][o0];
        float4 r;
        r.x = u4.x*e4.x + w4.x;
        r.y = u4.y*e4.y + w4.y;
        r.z = u4.z*e4.z + w4.z;
        r.w = u4.w*e4.w + w4.w;
        outp[p*256 + t] = r;
    }
}

// ---------------------------------------------------------------------------
// Fallback: proven single fused kernel (used only if ws is too small)
// ---------------------------------------------------------------------------
__global__ __launch_bounds__(256) void deq_orbital_fused(
    const float* __restrict__ x, const float* __restrict__ r_ei,
    const float* __restrict__ W_orb, const float* __restrict__ b_orb,
    const float* __restrict__ W_env, const float* __restrict__ w_ion,
    float* __restrict__ out)
{
    __shared__ float sx[NE][DF];
    __shared__ float sworb[2*DF][NORB];
    __shared__ float sr[NE][NION*3];
    __shared__ float swe[NION*3*NORB*3];
    __shared__ float sU[NE][NORB];
    __shared__ float sV[NE][NORB];
    __shared__ float sE[NE][NORB];
    __shared__ float sb[NORB];
    __shared__ float swion[NION];

    const int t   = threadIdx.x;
    const int blk = blockIdx.x;
    const int s   = blk >> 10;
    const int b   = blk & (BATCH - 1);

    {
        const float4* xg = (const float4*)(x + (size_t)(b*NELEC + s*NE) * DF);
        ((float4*)&sx[0][0])[t] = xg[t];
    }
    {
        const float4* wg = (const float4*)(W_orb + (size_t)s * 2*DF*NORB);
        float4* d = (float4*)&sworb[0][0];
        d[t] = wg[t]; d[t + 256] = wg[t + 256];
    }
    {
        const float4* rg = (const float4*)(r_ei + (size_t)(b*NELEC + s*NE) * NION * 3);
        float4* d = (float4*)&sr[0][0];
        d[t] = rg[t];
        if (t < 128) d[t + 256] = rg[t + 256];
    }
    {
        const float4* weg = (const float4*)(W_env + (size_t)s * NION*3*NORB*3);
        float4* d = (float4*)swe;
        for (int j = t; j < 1152; j += 256) d[j] = weg[j];
    }
    if (t < NORB) sb[t]    = b_orb[s*NORB + t];
    if (t < NION) swion[t] = w_ion[s*NION + t];
    __syncthreads();

    const int o  = t & 31;
    const int ng = t >> 5;
    float u_acc[4], v_acc[4];
    #pragma unroll
    for (int uu = 0; uu < 4; ++uu) { u_acc[uu] = 0.f; v_acc[uu] = 0.f; }
    #pragma unroll
    for (int d = 0; d < DF; ++d) {
        const float w0 = sworb[d][o];
        const float w1 = sworb[DF + d][o];
        #pragma unroll
        for (int uu = 0; uu < 4; ++uu) {
            const float xv = sx[ng*4 + uu][d];
            u_acc[uu] += xv * w0;
            v_acc[uu] += xv * w1;
        }
    }
    #pragma unroll
    for (int uu = 0; uu < 4; ++uu) {
        sU[ng*4 + uu][o] = u_acc[uu];
        sV[ng*4 + uu][o] = v_acc[uu];
    }
    #pragma unroll
    for (int uu = 0; uu < 4; ++uu) {
        const int nn = ng*4 + uu;
        float acc = 0.f;
        #pragma unroll
        for (int i = 0; i < NION; ++i) {
            const float r0 = sr[nn][i*3 + 0];
            const float r1 = sr[nn][i*3 + 1];
            const float r2 = sr[nn][i*3 + 2];
            const float* wp = &swe[i*3*NORB*3 + o*3];
            const float s0 = r0*wp[0] + r1*wp[NORB*3    ] + r2*wp[2*NORB*3    ];
            const float s1 = r0*wp[1] + r1*wp[NORB*3 + 1] + r2*wp[2*NORB*3 + 1];
            const float s2 = r0*wp[2] + r1*wp[NORB*3 + 2] + r2*wp[2*NORB*3 + 2];
            const float dist = sqrtf(s0*s0 + s1*s1 + s2*s2);
            acc += __expf(-dist) * swion[i];
        }
        sE[nn][o] = acc;
        sV[nn][o] = (v_acc[uu] + sb[o]) * acc;
    }
    __syncthreads();

    const int io = t >> 3;
    const int o0 = (t & 7) * 4;
    const float4 e4 = *(const float4*)&sE[io][o0];
    const float4 w4 = *(const float4*)&sV[io][o0];
    float4* outp = (float4*)(out + (size_t)blk * (NE*NE*NORB));
    #pragma unroll
    for (int p = 0; p < NE; ++p) {
        const float4 u4 = *(const float4*)&sU[p][o0];
        float4 r;
        r.x = u4.x*e4.x + w4.x;
        r.y = u4.y*e4.y + w4.y;
        r.z = u4.z*e4.z + w4.z;
        r.w = u4.w*e4.w + w4.w;
        outp[p*256 + t] = r;
    }
}

extern "C" void kernel_launch(void* const* d_in, const int* in_sizes, int n_in,
                              void* d_out, int out_size, void* d_ws, size_t ws_size,
                              hipStream_t stream) {
    const float* x     = (const float*)d_in[0];
    const float* r_ei  = (const float*)d_in[1];
    const float* W_orb = (const float*)d_in[2];
    const float* b_orb = (const float*)d_in[3];
    const float* W_env = (const float*)d_in[4];
    const float* w_ion = (const float*)d_in[5];
    float* out = (float*)d_out;

    if (ws_size >= WS_NEEDED) {
        float* Mg = (float*)d_ws;
        float* Uf = Mg + M_PAD;
        float* Ef = Uf + FACT_FLOATS;
        float* Wf = Ef + FACT_FLOATS;
        k0_gram<<<4, 256, 0, stream>>>(W_env, Mg);
        k1_factors<<<NSB, 256, 0, stream>>>(x, r_ei, W_orb, b_orb, w_ion, Mg,
                                            Uf, Ef, Wf);
        k2_expand<<<NSB, 256, 0, stream>>>(Uf, Ef, Wf, out);
    } else {
        deq_orbital_fused<<<NSB, 256, 0, stream>>>(x, r_ei, W_orb, b_orb,
                                                   W_env, w_ion, out);
    }
}